// Round 1
// baseline (247.585 us; speedup 1.0000x reference)
//
#include <hip/hip_runtime.h>

// B=2, S=2048, H=1024, NUM_HEAD=16, HEAD=64
#define BATCH 2
#define S_LEN 2048
#define HDIM  1024
#define NHEAD 16
#define HD    64
#define NEGBIAS -1e10f
#define LOG2E 1.44269504088896f

typedef __attribute__((ext_vector_type(8))) _Float16 half8;  // 8 f16 in 4 VGPRs
typedef __attribute__((ext_vector_type(4))) _Float16 half4;  // 4 f16 in 2 VGPRs
typedef __attribute__((ext_vector_type(4))) float   f32x4;   // MFMA C/D frag

// ---------------------------------------------------------------------------
// Fused projection GEMM (fp16 MFMA): Y = X @ W^T + b, fp32 inputs converted
// inline.  z=0,1 -> [B,NH,S,HD]; z=2 -> V transposed [B,NH,HD,S].
// 128x128 tile, BK=32, register-prefetch pipeline.
// z==0 (Q) output is PRE-SCALED by log2(e) so attention can use exp2 directly.
// ---------------------------------------------------------------------------
__global__ __launch_bounds__(256) void proj_gemm_f16(
    const float* __restrict__ Xq, const float* __restrict__ Wq, const float* __restrict__ bq,
    const float* __restrict__ Xk, const float* __restrict__ Wk, const float* __restrict__ bk,
    const float* __restrict__ Xv, const float* __restrict__ Wv, const float* __restrict__ bv,
    _Float16* __restrict__ Qb, _Float16* __restrict__ Kb, _Float16* __restrict__ Vtb)
{
    const int z = blockIdx.z;
    const float* X    = (z == 0) ? Xq : (z == 1) ? Xk : Xv;
    const float* W    = (z == 0) ? Wq : (z == 1) ? Wk : Wv;
    const float* bias = (z == 0) ? bq : (z == 1) ? bk : bv;
    _Float16* Y       = (z == 0) ? Qb : (z == 1) ? Kb : Vtb;

    const int n0 = blockIdx.x * 128;
    const int m0 = blockIdx.y * 128;

    __shared__ __align__(16) _Float16 As[128][40];  // [m][k], pad 40
    __shared__ __align__(16) _Float16 Bs[128][40];  // [n][k]

    const int t    = threadIdx.x;
    const int w    = t >> 6;
    const int lane = t & 63;
    const int quad = lane >> 4;
    const int lc   = lane & 15;
    const int wm   = (w >> 1) * 64;
    const int wn   = (w & 1) * 64;

    const f32x4 fzero = {0.f, 0.f, 0.f, 0.f};
    f32x4 acc[4][4];
#pragma unroll
    for (int i = 0; i < 4; i++)
#pragma unroll
        for (int j = 0; j < 4; j++) acc[i][j] = fzero;

    const int srow = t >> 2;   // 0..63 (two halves: srow, srow+64)
    const int sc   = t & 3;    // 8-elem chunk within the 32-elem k slice

    float4 xa[2][2], wa[2][2];          // prefetch registers
#define PROJ_ISSUE(K0)                                                        \
    {                                                                         \
        _Pragma("unroll")                                                     \
        for (int hf = 0; hf < 2; hf++) {                                      \
            const float* gx = X + (size_t)(m0 + srow + hf * 64) * HDIM + (K0) + sc * 8; \
            xa[hf][0] = *(const float4*)gx;                                   \
            xa[hf][1] = *(const float4*)(gx + 4);                             \
            const float* gw = W + (size_t)(n0 + srow + hf * 64) * HDIM + (K0) + sc * 8; \
            wa[hf][0] = *(const float4*)gw;                                   \
            wa[hf][1] = *(const float4*)(gw + 4);                             \
        }                                                                     \
    }

    PROJ_ISSUE(0)

    for (int k0 = 0; k0 < HDIM; k0 += 32) {
        if (k0) __syncthreads();        // prev iter done reading LDS
#pragma unroll
        for (int hf = 0; hf < 2; hf++) {
            int row = srow + hf * 64;
            half8 vx;
            vx[0] = (_Float16)xa[hf][0].x; vx[1] = (_Float16)xa[hf][0].y;
            vx[2] = (_Float16)xa[hf][0].z; vx[3] = (_Float16)xa[hf][0].w;
            vx[4] = (_Float16)xa[hf][1].x; vx[5] = (_Float16)xa[hf][1].y;
            vx[6] = (_Float16)xa[hf][1].z; vx[7] = (_Float16)xa[hf][1].w;
            *(half8*)&As[row][sc * 8] = vx;
            half8 vw;
            vw[0] = (_Float16)wa[hf][0].x; vw[1] = (_Float16)wa[hf][0].y;
            vw[2] = (_Float16)wa[hf][0].z; vw[3] = (_Float16)wa[hf][0].w;
            vw[4] = (_Float16)wa[hf][1].x; vw[5] = (_Float16)wa[hf][1].y;
            vw[6] = (_Float16)wa[hf][1].z; vw[7] = (_Float16)wa[hf][1].w;
            *(half8*)&Bs[row][sc * 8] = vw;
        }
        __syncthreads();

        if (k0 + 32 < HDIM) PROJ_ISSUE(k0 + 32)   // overlap with MFMAs below

        half8 af[4], bf[4];
#pragma unroll
        for (int mt = 0; mt < 4; mt++)
            af[mt] = *(const half8*)&As[wm + mt * 16 + lc][quad * 8];
#pragma unroll
        for (int nt = 0; nt < 4; nt++)
            bf[nt] = *(const half8*)&Bs[wn + nt * 16 + lc][quad * 8];
#pragma unroll
        for (int mt = 0; mt < 4; mt++)
#pragma unroll
            for (int nt = 0; nt < 4; nt++)
                acc[mt][nt] = __builtin_amdgcn_mfma_f32_16x16x32_f16(
                    af[mt], bf[nt], acc[mt][nt], 0, 0, 0);
    }

#pragma unroll
    for (int nt = 0; nt < 4; nt++) {
        const int n = n0 + wn + nt * 16 + lc;          // h*64 + d
        const float bv_ = bias[n];
        const int h = n >> 6, d = n & 63;
#pragma unroll
        for (int mt = 0; mt < 4; mt++) {
#pragma unroll
            for (int r = 0; r < 4; r++) {
                const int m = m0 + wm + mt * 16 + quad * 4 + r;   // b*S + s
                const int b = m >> 11, s = m & (S_LEN - 1);
                const int bh = b * NHEAD + h;
                float y = acc[mt][nt][r] + bv_;
                if (z == 0) y *= LOG2E;                 // exp2-fold for attn
                _Float16 val = (_Float16)y;
                if (z == 2)
                    Y[((size_t)bh * HD + d) * S_LEN + s] = val;          // V^T
                else
                    Y[((size_t)bh * S_LEN + s) * HD + d] = val;          // Q,K
            }
        }
    }
}

// ---------------------------------------------------------------------------
// Flash attention v2.  Changes vs previous round (VALU-bound @51% busy,
// 2 blocks/CU grid-limited occupancy):
//   * 64-row q-tiles -> grid 1024 = 4 blocks/CU = 4 waves/SIMD (was 2).
//   * XCD-aware block swizzle: 32 q-blocks of 4 (b,h) pairs share one XCD's
//     L2 for K/V (4*512KB = 2MB, L2-resident).
//   * Softmax VALU diet: Q pre-scaled by log2e -> bare exp2f (no v_mul);
//     v_cvt_pkrtz packed P conversion; defer-max rescale (threshold 8 in
//     log2 domain) skips the o-rescale on most tiles.
// Orientation unchanged: S^T = K.Q^T, O^T = V^T.P^T (transposed MFMA).
// ---------------------------------------------------------------------------
__global__ __launch_bounds__(256, 4) void flash_attn_mfma(
    const _Float16* __restrict__ Qb, const _Float16* __restrict__ Kb,
    const _Float16* __restrict__ Vtb, const int* __restrict__ mask,
    float* __restrict__ out)
{
    // XCD swizzle: hw round-robins blockIdx%8 across XCDs; give each XCD a
    // contiguous chunk of 128 logical blocks = 4 bh groups x 32 q-tiles.
    const int bid = blockIdx.x;                  // 0..1023
    const int swz = (bid & 7) * 128 + (bid >> 3);
    const int qt = swz & 31;                     // 32 q-tiles of 64 rows
    const int bh = swz >> 5;                     // 0..31
    const int b  = bh >> 4;
    const int h  = bh & (NHEAD - 1);

    __shared__ __align__(16) _Float16 Ks [64][72];      // [key][d]
    __shared__ __align__(16) _Float16 Vts[64][72];      // [d][key]
    __shared__ __align__(16) _Float16 Ps [4][16][72];   // per-wave P, [q][key]
    __shared__ float biasS[64];                         // mask bias per key

    const int t    = threadIdx.x;
    const int w    = t >> 6;
    const int lane = t & 63;
    const int quad = lane >> 4;
    const int lc   = lane & 15;

    const _Float16* Kbase = Kb  + (size_t)bh * S_LEN * HD;
    const _Float16* Vbase = Vtb + (size_t)bh * HD * S_LEN;
    const int* mbase = mask + b * S_LEN;

    // Q B-frag: wave owns 16 q-rows, q-row = qt*64 + w*16 + lc
    const int qrow = qt * 64 + w * 16 + lc;
    half8 qf[2];
#pragma unroll
    for (int s = 0; s < 2; s++)
        qf[s] = *(const half8*)(Qb + ((size_t)bh * S_LEN + qrow) * HD
                                + s * 32 + quad * 8);

    const f32x4 fzero = {0.f, 0.f, 0.f, 0.f};
    f32x4 o[4];                         // O^T: d = nt*16+quad*4+r, q = lc
#pragma unroll
    for (int nt = 0; nt < 4; nt++) o[nt] = fzero;
    float mrun = -3.0e38f;
    float lrun = 0.f;

    // staging geometry: chunk c = t + 256*i -> row c>>3, col (c&7)*8
    const int rr0 = t >> 3,          cc0 = (t & 7) * 8;
    const int rr1 = (t + 256) >> 3,  cc1 = (t & 7) * 8;   // rows 32..63

    half8 kpre[2], vpre[2];
    int   mpre;
#define ATTN_ISSUE(KT)                                                        \
    {                                                                         \
        kpre[0] = *(const half8*)(Kbase + (size_t)((KT) + rr0) * HD + cc0);   \
        kpre[1] = *(const half8*)(Kbase + (size_t)((KT) + rr1) * HD + cc1);   \
        vpre[0] = *(const half8*)(Vbase + (size_t)rr0 * S_LEN + (KT) + cc0);  \
        vpre[1] = *(const half8*)(Vbase + (size_t)rr1 * S_LEN + (KT) + cc1);  \
        mpre    = mbase[(KT) + (t & 63)];                                     \
    }

    ATTN_ISSUE(0)

    for (int kt = 0; kt < S_LEN; kt += 64) {
        if (kt) __syncthreads();        // prev iter done reading LDS
        *(half8*)&Ks [rr0][cc0] = kpre[0];
        *(half8*)&Ks [rr1][cc1] = kpre[1];
        *(half8*)&Vts[rr0][cc0] = vpre[0];
        *(half8*)&Vts[rr1][cc1] = vpre[1];
        if (t < 64) biasS[t] = mpre ? 0.f : NEGBIAS;
        __syncthreads();

        if (kt + 64 < S_LEN) ATTN_ISSUE(kt + 64)   // overlap with compute

        // S^T = K.Q^T  (scores already in log2 domain: Q pre-scaled)
        f32x4 scf[4];
#pragma unroll
        for (int tt = 0; tt < 4; tt++) scf[tt] = fzero;
#pragma unroll
        for (int s = 0; s < 2; s++) {
#pragma unroll
            for (int tt = 0; tt < 4; tt++) {
                half8 kf = *(const half8*)&Ks[tt * 16 + lc][s * 32 + quad * 8];
                scf[tt] = __builtin_amdgcn_mfma_f32_16x16x32_f16(kf, qf[s], scf[tt], 0, 0, 0);
            }
        }

        // mask bias: score (tt,r) is key tt*16+quad*4+r
#pragma unroll
        for (int tt = 0; tt < 4; tt++) {
            float4 b4 = *(const float4*)&biasS[tt * 16 + quad * 4];
            scf[tt][0] += b4.x; scf[tt][1] += b4.y;
            scf[tt][2] += b4.z; scf[tt][3] += b4.w;
        }

        // per-lane online softmax, one q-row per lc (log2 domain)
        float mx = scf[0][0];
#pragma unroll
        for (int tt = 0; tt < 4; tt++)
#pragma unroll
            for (int r = 0; r < 4; r++) mx = fmaxf(mx, scf[tt][r]);
        mx = fmaxf(mx, __shfl_xor(mx, 16));
        mx = fmaxf(mx, __shfl_xor(mx, 32));

        // defer-max (T13): skip the o-rescale unless max grew past threshold.
        // While skipped, P is bounded by 2^8 = 256 (fine in f16).
        if (!__all(mx <= mrun + 8.f)) {
            float mn = fmaxf(mrun, mx);
            float al = exp2f(mrun - mn);
            lrun *= al;
#pragma unroll
            for (int nt = 0; nt < 4; nt++) {
                o[nt][0] *= al; o[nt][1] *= al;
                o[nt][2] *= al; o[nt][3] *= al;
            }
            mrun = mn;
        }

        float ls = 0.f;
#pragma unroll
        for (int tt = 0; tt < 4; tt++)
#pragma unroll
            for (int r = 0; r < 4; r++) {
                float p = exp2f(scf[tt][r] - mrun);   // bare v_exp_f32
                scf[tt][r] = p;
                ls += p;
            }
        ls += __shfl_xor(ls, 16);
        ls += __shfl_xor(ls, 32);
        lrun += ls;

        // P rows (q-major): Ps[w][lc][key], packed RTZ conversion (2 insts/4)
#pragma unroll
        for (int tt = 0; tt < 4; tt++) {
            auto pk01 = __builtin_amdgcn_cvt_pkrtz(scf[tt][0], scf[tt][1]);
            auto pk23 = __builtin_amdgcn_cvt_pkrtz(scf[tt][2], scf[tt][3]);
            auto pk   = __builtin_shufflevector(pk01, pk23, 0, 1, 2, 3);
            *(decltype(pk)*)&Ps[w][lc][tt * 16 + quad * 4] = pk;
        }

        // O^T += V^T.P^T
#pragma unroll
        for (int s = 0; s < 2; s++) {
            half8 pf = *(const half8*)&Ps[w][lc][s * 32 + quad * 8];
#pragma unroll
            for (int nt = 0; nt < 4; nt++) {
                half8 vf = *(const half8*)&Vts[nt * 16 + lc][s * 32 + quad * 8];
                o[nt] = __builtin_amdgcn_mfma_f32_16x16x32_f16(vf, pf, o[nt], 0, 0, 0);
            }
        }
    }

    // epilogue: lane owns q-row lc; contiguous float4 stores
    const float inv = 1.f / lrun;
    const size_t rowb = ((size_t)b * S_LEN + qrow) * HDIM + h * HD;
#pragma unroll
    for (int nt = 0; nt < 4; nt++) {
        float4 v;
        v.x = o[nt][0] * inv; v.y = o[nt][1] * inv;
        v.z = o[nt][2] * inv; v.w = o[nt][3] * inv;
        *(float4*)&out[rowb + nt * 16 + quad * 4] = v;
    }
}

// ---------------------------------------------------------------------------
extern "C" void kernel_launch(void* const* d_in, const int* in_sizes, int n_in,
                              void* d_out, int out_size, void* d_ws, size_t ws_size,
                              hipStream_t stream) {
    const float* query = (const float*)d_in[0];
    const float* key   = (const float*)d_in[1];
    const float* value = (const float*)d_in[2];
    const int*   mask  = (const int*)  d_in[3];
    const float* Wq    = (const float*)d_in[4];
    const float* bq    = (const float*)d_in[5];
    const float* Wk    = (const float*)d_in[6];
    const float* bk    = (const float*)d_in[7];
    const float* Wv    = (const float*)d_in[8];
    const float* bv    = (const float*)d_in[9];
    float* out = (float*)d_out;

    const size_t nElem = (size_t)BATCH * S_LEN * HDIM;          // 4M
    if (ws_size < 3 * nElem * sizeof(_Float16)) return;         // 24 MB
    _Float16* Qb  = (_Float16*)d_ws;
    _Float16* Kb  = Qb + nElem;
    _Float16* Vtb = Kb + nElem;

    dim3 gproj(HDIM / 128, (BATCH * S_LEN) / 128, 3);           // (8, 32, 3)
    proj_gemm_f16<<<gproj, 256, 0, stream>>>(query, Wq, bq, key, Wk, bk,
                                             value, Wv, bv, Qb, Kb, Vtb);

    flash_attn_mfma<<<BATCH * NHEAD * (S_LEN / 64), 256, 0, stream>>>(
        Qb, Kb, Vtb, mask, out);
}

// Round 2
// 247.108 us; speedup vs baseline: 1.0019x; 1.0019x over previous
//
#include <hip/hip_runtime.h>

// B=2, S=2048, H=1024, NUM_HEAD=16, HEAD=64
#define BATCH 2
#define S_LEN 2048
#define HDIM  1024
#define NHEAD 16
#define HD    64
#define NEGBIAS -1e10f
#define LOG2E 1.44269504088896f

typedef __attribute__((ext_vector_type(8))) _Float16 half8;  // 8 f16 in 4 VGPRs
typedef __attribute__((ext_vector_type(4))) _Float16 half4;  // 4 f16 in 2 VGPRs
typedef __attribute__((ext_vector_type(4))) float   f32x4;   // MFMA C/D frag

// ---------------------------------------------------------------------------
// Fused projection GEMM (fp16 MFMA): Y = X @ W^T + b, fp32 inputs converted
// inline.  z=0,1 -> [B,NH,S,HD]; z=2 -> V transposed [B,NH,HD,S].
// 128x128 tile, BK=32, register-prefetch pipeline.
// z==0 (Q) output is PRE-SCALED by log2(e) so attention can use exp2 directly.
// ---------------------------------------------------------------------------
__global__ __launch_bounds__(256) void proj_gemm_f16(
    const float* __restrict__ Xq, const float* __restrict__ Wq, const float* __restrict__ bq,
    const float* __restrict__ Xk, const float* __restrict__ Wk, const float* __restrict__ bk,
    const float* __restrict__ Xv, const float* __restrict__ Wv, const float* __restrict__ bv,
    _Float16* __restrict__ Qb, _Float16* __restrict__ Kb, _Float16* __restrict__ Vtb)
{
    const int z = blockIdx.z;
    const float* X    = (z == 0) ? Xq : (z == 1) ? Xk : Xv;
    const float* W    = (z == 0) ? Wq : (z == 1) ? Wk : Wv;
    const float* bias = (z == 0) ? bq : (z == 1) ? bk : bv;
    _Float16* Y       = (z == 0) ? Qb : (z == 1) ? Kb : Vtb;

    const int n0 = blockIdx.x * 128;
    const int m0 = blockIdx.y * 128;

    __shared__ __align__(16) _Float16 As[128][40];  // [m][k], pad 40
    __shared__ __align__(16) _Float16 Bs[128][40];  // [n][k]

    const int t    = threadIdx.x;
    const int w    = t >> 6;
    const int lane = t & 63;
    const int quad = lane >> 4;
    const int lc   = lane & 15;
    const int wm   = (w >> 1) * 64;
    const int wn   = (w & 1) * 64;

    const f32x4 fzero = {0.f, 0.f, 0.f, 0.f};
    f32x4 acc[4][4];
#pragma unroll
    for (int i = 0; i < 4; i++)
#pragma unroll
        for (int j = 0; j < 4; j++) acc[i][j] = fzero;

    const int srow = t >> 2;   // 0..63 (two halves: srow, srow+64)
    const int sc   = t & 3;    // 8-elem chunk within the 32-elem k slice

    float4 xa[2][2], wa[2][2];          // prefetch registers
#define PROJ_ISSUE(K0)                                                        \
    {                                                                         \
        _Pragma("unroll")                                                     \
        for (int hf = 0; hf < 2; hf++) {                                      \
            const float* gx = X + (size_t)(m0 + srow + hf * 64) * HDIM + (K0) + sc * 8; \
            xa[hf][0] = *(const float4*)gx;                                   \
            xa[hf][1] = *(const float4*)(gx + 4);                             \
            const float* gw = W + (size_t)(n0 + srow + hf * 64) * HDIM + (K0) + sc * 8; \
            wa[hf][0] = *(const float4*)gw;                                   \
            wa[hf][1] = *(const float4*)(gw + 4);                             \
        }                                                                     \
    }

    PROJ_ISSUE(0)

    for (int k0 = 0; k0 < HDIM; k0 += 32) {
        if (k0) __syncthreads();        // prev iter done reading LDS
#pragma unroll
        for (int hf = 0; hf < 2; hf++) {
            int row = srow + hf * 64;
            half8 vx;
            vx[0] = (_Float16)xa[hf][0].x; vx[1] = (_Float16)xa[hf][0].y;
            vx[2] = (_Float16)xa[hf][0].z; vx[3] = (_Float16)xa[hf][0].w;
            vx[4] = (_Float16)xa[hf][1].x; vx[5] = (_Float16)xa[hf][1].y;
            vx[6] = (_Float16)xa[hf][1].z; vx[7] = (_Float16)xa[hf][1].w;
            *(half8*)&As[row][sc * 8] = vx;
            half8 vw;
            vw[0] = (_Float16)wa[hf][0].x; vw[1] = (_Float16)wa[hf][0].y;
            vw[2] = (_Float16)wa[hf][0].z; vw[3] = (_Float16)wa[hf][0].w;
            vw[4] = (_Float16)wa[hf][1].x; vw[5] = (_Float16)wa[hf][1].y;
            vw[6] = (_Float16)wa[hf][1].z; vw[7] = (_Float16)wa[hf][1].w;
            *(half8*)&Bs[row][sc * 8] = vw;
        }
        __syncthreads();

        if (k0 + 32 < HDIM) PROJ_ISSUE(k0 + 32)   // overlap with MFMAs below

        half8 af[4], bf[4];
#pragma unroll
        for (int mt = 0; mt < 4; mt++)
            af[mt] = *(const half8*)&As[wm + mt * 16 + lc][quad * 8];
#pragma unroll
        for (int nt = 0; nt < 4; nt++)
            bf[nt] = *(const half8*)&Bs[wn + nt * 16 + lc][quad * 8];
#pragma unroll
        for (int mt = 0; mt < 4; mt++)
#pragma unroll
            for (int nt = 0; nt < 4; nt++)
                acc[mt][nt] = __builtin_amdgcn_mfma_f32_16x16x32_f16(
                    af[mt], bf[nt], acc[mt][nt], 0, 0, 0);
    }

#pragma unroll
    for (int nt = 0; nt < 4; nt++) {
        const int n = n0 + wn + nt * 16 + lc;          // h*64 + d
        const float bv_ = bias[n];
        const int h = n >> 6, d = n & 63;
#pragma unroll
        for (int mt = 0; mt < 4; mt++) {
#pragma unroll
            for (int r = 0; r < 4; r++) {
                const int m = m0 + wm + mt * 16 + quad * 4 + r;   // b*S + s
                const int b = m >> 11, s = m & (S_LEN - 1);
                const int bh = b * NHEAD + h;
                float y = acc[mt][nt][r] + bv_;
                if (z == 0) y *= LOG2E;                 // exp2-fold for attn
                _Float16 val = (_Float16)y;
                if (z == 2)
                    Y[((size_t)bh * HD + d) * S_LEN + s] = val;          // V^T
                else
                    Y[((size_t)bh * S_LEN + s) * HD + d] = val;          // Q,K
            }
        }
    }
}

// ---------------------------------------------------------------------------
// Flash attention v3.  Round-1 post-mortem: 64-row tiles doubled per-MFMA LDS
// traffic (conflicts 7.3M->11.5M cyc) and regressed 81->95us.  This round:
//   * REVERT to 128-row q-tiles, 4 waves, 2 q-groups/wave (2 MFMAs per LDS
//     read -- best measured amortization).
//   * KEEP the geometry-independent wins: exp2 log2-domain softmax (Q
//     pre-scaled by log2e), defer-max rescale (T13), cvt_pkrtz packed P,
//     XCD-aware block swizzle (FETCH 69.8MB -> 12.4MB last round).
//   * NEW: XOR-swizzled LDS layout (T2, byte ^= (row&7)<<4) for Ks/Vts/Ps,
//     unpadded [row][64] f16 (128B rows).  Kills the stride-144 bank
//     conflicts (~15% of cycles in round 0).  Both write & read sides are
//     register-staged so the swizzle is applied consistently.
// Orientation unchanged: S^T = K.Q^T, O^T = V^T.P^T (transposed MFMA).
// ---------------------------------------------------------------------------

// byte offset of (row, colbyte) in a swizzled [64][128B] LDS tile
#define SWZB(row, cb) (((row) << 7) + ((cb) ^ (((row) & 7) << 4)))

__global__ __launch_bounds__(256) void flash_attn_mfma(
    const _Float16* __restrict__ Qb, const _Float16* __restrict__ Kb,
    const _Float16* __restrict__ Vtb, const int* __restrict__ mask,
    float* __restrict__ out)
{
    // XCD swizzle: hw round-robins blockIdx%8 across XCDs; give each XCD a
    // contiguous chunk of 64 logical blocks = 4 bh groups x 16 q-tiles, so
    // its L2 holds K/V for just 4 heads (4 x 512KB = 2MB, L2-resident).
    const int bid = blockIdx.x;                  // 0..511
    const int swz = (bid & 7) * 64 + (bid >> 3);
    const int qt = swz & 15;                     // 16 q-tiles of 128 rows
    const int bh = swz >> 4;                     // 0..31
    const int b  = bh >> 4;
    const int h  = bh & (NHEAD - 1);

    __shared__ __align__(16) _Float16 KsBuf [64 * 64];      // swz [key][d]
    __shared__ __align__(16) _Float16 VtsBuf[64 * 64];      // swz [d][key]
    __shared__ __align__(16) _Float16 PsBuf [4][32 * 64];   // swz per-wave [q][key]
    __shared__ float biasS[64];                             // mask bias per key

    const int t    = threadIdx.x;
    const int w    = t >> 6;
    const int lane = t & 63;
    const int quad = lane >> 4;
    const int lc   = lane & 15;

    char* KsB  = (char*)KsBuf;
    char* VtsB = (char*)VtsBuf;
    char* PsB  = (char*)PsBuf[w];

    const _Float16* Kbase = Kb  + (size_t)bh * S_LEN * HD;
    const _Float16* Vbase = Vtb + (size_t)bh * HD * S_LEN;
    const int* mbase = mask + b * S_LEN;

    // Q B-frags: qg in {0,1}, q-row = qt*128 + w*32 + qg*16 + lc
    half8 qf[2][2];
#pragma unroll
    for (int qg = 0; qg < 2; qg++) {
        const int qrow = qt * 128 + w * 32 + qg * 16 + lc;
#pragma unroll
        for (int s = 0; s < 2; s++)
            qf[qg][s] = *(const half8*)(Qb + ((size_t)bh * S_LEN + qrow) * HD
                                        + s * 32 + quad * 8);
    }

    const f32x4 fzero = {0.f, 0.f, 0.f, 0.f};
    f32x4 o[2][4];                      // O^T per qg: d = nt*16+quad*4+r, q = lc
#pragma unroll
    for (int qg = 0; qg < 2; qg++)
#pragma unroll
        for (int nt = 0; nt < 4; nt++) o[qg][nt] = fzero;
    float mrun[2] = {-3.0e38f, -3.0e38f};
    float lrun[2] = {0.f, 0.f};

    // staging geometry: chunk c = t + 256*i -> row c>>3, colbyte (c&7)*16
    const int rr0 = t >> 3,          cb0 = (t & 7) * 16;
    const int rr1 = (t + 256) >> 3;                       // rows 32..63

    half8 kpre[2], vpre[2];
    int   mpre;
#define ATTN_ISSUE(KT)                                                          \
    {                                                                           \
        kpre[0] = *(const half8*)(Kbase + (size_t)((KT) + rr0) * HD + (cb0 >> 1)); \
        kpre[1] = *(const half8*)(Kbase + (size_t)((KT) + rr1) * HD + (cb0 >> 1)); \
        vpre[0] = *(const half8*)(Vbase + (size_t)rr0 * S_LEN + (KT) + (cb0 >> 1)); \
        vpre[1] = *(const half8*)(Vbase + (size_t)rr1 * S_LEN + (KT) + (cb0 >> 1)); \
        mpre    = mbase[(KT) + (t & 63)];                                       \
    }

    ATTN_ISSUE(0)

    for (int kt = 0; kt < S_LEN; kt += 64) {
        if (kt) __syncthreads();        // prev iter done reading LDS
        *(half8*)(KsB  + SWZB(rr0, cb0)) = kpre[0];
        *(half8*)(KsB  + SWZB(rr1, cb0)) = kpre[1];
        *(half8*)(VtsB + SWZB(rr0, cb0)) = vpre[0];
        *(half8*)(VtsB + SWZB(rr1, cb0)) = vpre[1];
        if (t < 64) biasS[t] = mpre ? 0.f : NEGBIAS;
        __syncthreads();

        if (kt + 64 < S_LEN) ATTN_ISSUE(kt + 64)   // overlap with compute

        // S^T = K.Q^T : each kf read feeds both qg MFMAs
        f32x4 scf[2][4];
#pragma unroll
        for (int qg = 0; qg < 2; qg++)
#pragma unroll
            for (int tt = 0; tt < 4; tt++) scf[qg][tt] = fzero;
#pragma unroll
        for (int s = 0; s < 2; s++) {
#pragma unroll
            for (int tt = 0; tt < 4; tt++) {
                half8 kf = *(const half8*)(KsB + SWZB(tt * 16 + lc, s * 64 + quad * 16));
                scf[0][tt] = __builtin_amdgcn_mfma_f32_16x16x32_f16(kf, qf[0][s], scf[0][tt], 0, 0, 0);
                scf[1][tt] = __builtin_amdgcn_mfma_f32_16x16x32_f16(kf, qf[1][s], scf[1][tt], 0, 0, 0);
            }
        }

        // mask bias: score (tt,r) is key tt*16+quad*4+r
#pragma unroll
        for (int tt = 0; tt < 4; tt++) {
            float4 b4 = *(const float4*)&biasS[tt * 16 + quad * 4];
#pragma unroll
            for (int qg = 0; qg < 2; qg++) {
                scf[qg][tt][0] += b4.x; scf[qg][tt][1] += b4.y;
                scf[qg][tt][2] += b4.z; scf[qg][tt][3] += b4.w;
            }
        }

        // per-lane online softmax, one q-row per (qg, lc), log2 domain
#pragma unroll
        for (int qg = 0; qg < 2; qg++) {
            float mx = scf[qg][0][0];
#pragma unroll
            for (int tt = 0; tt < 4; tt++)
#pragma unroll
                for (int r = 0; r < 4; r++) mx = fmaxf(mx, scf[qg][tt][r]);
            mx = fmaxf(mx, __shfl_xor(mx, 16));
            mx = fmaxf(mx, __shfl_xor(mx, 32));

            // defer-max (T13): skip o-rescale unless max grew past threshold.
            // While skipped, P is bounded by 2^8 = 256 (fine in f16).
            if (!__all(mx <= mrun[qg] + 8.f)) {
                float mn = fmaxf(mrun[qg], mx);
                float al = exp2f(mrun[qg] - mn);
                lrun[qg] *= al;
#pragma unroll
                for (int nt = 0; nt < 4; nt++) {
                    o[qg][nt][0] *= al; o[qg][nt][1] *= al;
                    o[qg][nt][2] *= al; o[qg][nt][3] *= al;
                }
                mrun[qg] = mn;
            }

            float ls = 0.f;
#pragma unroll
            for (int tt = 0; tt < 4; tt++)
#pragma unroll
                for (int r = 0; r < 4; r++) {
                    float p = exp2f(scf[qg][tt][r] - mrun[qg]);   // bare v_exp_f32
                    scf[qg][tt][r] = p;
                    ls += p;
                }
            ls += __shfl_xor(ls, 16);
            ls += __shfl_xor(ls, 32);
            lrun[qg] += ls;

            // P rows (q-major): swz Ps[w][qg*16+lc][key], packed RTZ cvt
#pragma unroll
            for (int tt = 0; tt < 4; tt++) {
                auto pk01 = __builtin_amdgcn_cvt_pkrtz(scf[qg][tt][0], scf[qg][tt][1]);
                auto pk23 = __builtin_amdgcn_cvt_pkrtz(scf[qg][tt][2], scf[qg][tt][3]);
                auto pk   = __builtin_shufflevector(pk01, pk23, 0, 1, 2, 3);
                *(decltype(pk)*)(PsB + SWZB(qg * 16 + lc, tt * 32 + quad * 8)) = pk;
            }
        }

        // O^T += V^T.P^T : each vf read feeds both qg MFMAs
#pragma unroll
        for (int s = 0; s < 2; s++) {
            half8 pf0 = *(const half8*)(PsB + SWZB(lc,      s * 64 + quad * 16));
            half8 pf1 = *(const half8*)(PsB + SWZB(16 + lc, s * 64 + quad * 16));
#pragma unroll
            for (int nt = 0; nt < 4; nt++) {
                half8 vf = *(const half8*)(VtsB + SWZB(nt * 16 + lc, s * 64 + quad * 16));
                o[0][nt] = __builtin_amdgcn_mfma_f32_16x16x32_f16(vf, pf0, o[0][nt], 0, 0, 0);
                o[1][nt] = __builtin_amdgcn_mfma_f32_16x16x32_f16(vf, pf1, o[1][nt], 0, 0, 0);
            }
        }
    }

    // epilogue: lane owns q-row per qg; contiguous float4 stores
#pragma unroll
    for (int qg = 0; qg < 2; qg++) {
        const int qrow = qt * 128 + w * 32 + qg * 16 + lc;
        const float inv = 1.f / lrun[qg];
        const size_t rowb = ((size_t)b * S_LEN + qrow) * HDIM + h * HD;
#pragma unroll
        for (int nt = 0; nt < 4; nt++) {
            float4 v;
            v.x = o[qg][nt][0] * inv; v.y = o[qg][nt][1] * inv;
            v.z = o[qg][nt][2] * inv; v.w = o[qg][nt][3] * inv;
            *(float4*)&out[rowb + nt * 16 + quad * 4] = v;
        }
    }
}

// ---------------------------------------------------------------------------
extern "C" void kernel_launch(void* const* d_in, const int* in_sizes, int n_in,
                              void* d_out, int out_size, void* d_ws, size_t ws_size,
                              hipStream_t stream) {
    const float* query = (const float*)d_in[0];
    const float* key   = (const float*)d_in[1];
    const float* value = (const float*)d_in[2];
    const int*   mask  = (const int*)  d_in[3];
    const float* Wq    = (const float*)d_in[4];
    const float* bq    = (const float*)d_in[5];
    const float* Wk    = (const float*)d_in[6];
    const float* bk    = (const float*)d_in[7];
    const float* Wv    = (const float*)d_in[8];
    const float* bv    = (const float*)d_in[9];
    float* out = (float*)d_out;

    const size_t nElem = (size_t)BATCH * S_LEN * HDIM;          // 4M
    if (ws_size < 3 * nElem * sizeof(_Float16)) return;         // 24 MB
    _Float16* Qb  = (_Float16*)d_ws;
    _Float16* Kb  = Qb + nElem;
    _Float16* Vtb = Kb + nElem;

    dim3 gproj(HDIM / 128, (BATCH * S_LEN) / 128, 3);           // (8, 32, 3)
    proj_gemm_f16<<<gproj, 256, 0, stream>>>(query, Wq, bq, key, Wk, bk,
                                             value, Wv, bv, Qb, Kb, Vtb);

    flash_attn_mfma<<<BATCH * NHEAD * (S_LEN / 128), 256, 0, stream>>>(
        Qb, Kb, Vtb, mask, out);
}

// Round 4
// 234.432 us; speedup vs baseline: 1.0561x; 1.0541x over previous
//
#include <hip/hip_runtime.h>

// B=2, S=2048, H=1024, NUM_HEAD=16, HEAD=64
#define BATCH 2
#define S_LEN 2048
#define HDIM  1024
#define NHEAD 16
#define HD    64
#define NEGBIAS -1e10f
#define LOG2E 1.44269504088896f

typedef __attribute__((ext_vector_type(8))) _Float16 half8;  // 8 f16 in 4 VGPRs
typedef __attribute__((ext_vector_type(4))) _Float16 half4;  // 4 f16 in 2 VGPRs
typedef __attribute__((ext_vector_type(4))) float   f32x4;   // MFMA C/D frag
// cvt_pkrtz plumbing uses __fp16 vectors (the builtin's native type)
typedef __attribute__((ext_vector_type(2))) __fp16 fp16x2;
typedef __attribute__((ext_vector_type(4))) __fp16 fp16x4;
typedef __attribute__((ext_vector_type(8))) __fp16 fp16x8;

__device__ __forceinline__ float max3f(float a, float b, float c) {
    return fmaxf(fmaxf(a, b), c);        // clang fuses to v_max3_f32
}

// ---------------------------------------------------------------------------
// Fused projection GEMM (fp16 MFMA): Y = X @ W^T + b, fp32 inputs converted
// inline (packed cvt_pkrtz staging).  z=0,1 -> [B,NH,S,HD]; z=2 -> V
// transposed [B,NH,HD,S].  128x128 tile, BK=32, register-prefetch pipeline.
// z==0 (Q) output is PRE-SCALED by log2(e) so attention can use exp2 directly.
// ---------------------------------------------------------------------------
__global__ __launch_bounds__(256) void proj_gemm_f16(
    const float* __restrict__ Xq, const float* __restrict__ Wq, const float* __restrict__ bq,
    const float* __restrict__ Xk, const float* __restrict__ Wk, const float* __restrict__ bk,
    const float* __restrict__ Xv, const float* __restrict__ Wv, const float* __restrict__ bv,
    _Float16* __restrict__ Qb, _Float16* __restrict__ Kb, _Float16* __restrict__ Vtb)
{
    const int z = blockIdx.z;
    const float* X    = (z == 0) ? Xq : (z == 1) ? Xk : Xv;
    const float* W    = (z == 0) ? Wq : (z == 1) ? Wk : Wv;
    const float* bias = (z == 0) ? bq : (z == 1) ? bk : bv;
    _Float16* Y       = (z == 0) ? Qb : (z == 1) ? Kb : Vtb;

    const int n0 = blockIdx.x * 128;
    const int m0 = blockIdx.y * 128;

    __shared__ __align__(16) _Float16 As[128][40];  // [m][k], pad 40
    __shared__ __align__(16) _Float16 Bs[128][40];  // [n][k]

    const int t    = threadIdx.x;
    const int w    = t >> 6;
    const int lane = t & 63;
    const int quad = lane >> 4;
    const int lc   = lane & 15;
    const int wm   = (w >> 1) * 64;
    const int wn   = (w & 1) * 64;

    const f32x4 fzero = {0.f, 0.f, 0.f, 0.f};
    f32x4 acc[4][4];
#pragma unroll
    for (int i = 0; i < 4; i++)
#pragma unroll
        for (int j = 0; j < 4; j++) acc[i][j] = fzero;

    const int srow = t >> 2;   // 0..63 (two halves: srow, srow+64)
    const int sc   = t & 3;    // 8-elem chunk within the 32-elem k slice

    float4 xa[2][2], wa[2][2];          // prefetch registers
#define PROJ_ISSUE(K0)                                                        \
    {                                                                         \
        _Pragma("unroll")                                                     \
        for (int hf = 0; hf < 2; hf++) {                                      \
            const float* gx = X + (size_t)(m0 + srow + hf * 64) * HDIM + (K0) + sc * 8; \
            xa[hf][0] = *(const float4*)gx;                                   \
            xa[hf][1] = *(const float4*)(gx + 4);                             \
            const float* gw = W + (size_t)(n0 + srow + hf * 64) * HDIM + (K0) + sc * 8; \
            wa[hf][0] = *(const float4*)gw;                                   \
            wa[hf][1] = *(const float4*)(gw + 4);                             \
        }                                                                     \
    }

// packed fp32x8 -> f16x8 conversion (4 cvt_pkrtz)
#define PK8(dst, f0, f1)                                                      \
    {                                                                         \
        fp16x2 p0 = __builtin_amdgcn_cvt_pkrtz((f0).x, (f0).y);               \
        fp16x2 p1 = __builtin_amdgcn_cvt_pkrtz((f0).z, (f0).w);               \
        fp16x2 p2 = __builtin_amdgcn_cvt_pkrtz((f1).x, (f1).y);               \
        fp16x2 p3 = __builtin_amdgcn_cvt_pkrtz((f1).z, (f1).w);               \
        fp16x4 lo = __builtin_shufflevector(p0, p1, 0, 1, 2, 3);              \
        fp16x4 hi = __builtin_shufflevector(p2, p3, 0, 1, 2, 3);              \
        fp16x8 v8 = __builtin_shufflevector(lo, hi, 0, 1, 2, 3, 4, 5, 6, 7);  \
        dst = __builtin_bit_cast(half8, v8);                                  \
    }

    PROJ_ISSUE(0)

    for (int k0 = 0; k0 < HDIM; k0 += 32) {
        if (k0) __syncthreads();        // prev iter done reading LDS
#pragma unroll
        for (int hf = 0; hf < 2; hf++) {
            int row = srow + hf * 64;
            half8 vx, vw;
            PK8(vx, xa[hf][0], xa[hf][1])
            PK8(vw, wa[hf][0], wa[hf][1])
            *(half8*)&As[row][sc * 8] = vx;
            *(half8*)&Bs[row][sc * 8] = vw;
        }
        __syncthreads();

        if (k0 + 32 < HDIM) PROJ_ISSUE(k0 + 32)   // overlap with MFMAs below

        half8 af[4], bf[4];
#pragma unroll
        for (int mt = 0; mt < 4; mt++)
            af[mt] = *(const half8*)&As[wm + mt * 16 + lc][quad * 8];
#pragma unroll
        for (int nt = 0; nt < 4; nt++)
            bf[nt] = *(const half8*)&Bs[wn + nt * 16 + lc][quad * 8];
#pragma unroll
        for (int mt = 0; mt < 4; mt++)
#pragma unroll
            for (int nt = 0; nt < 4; nt++)
                acc[mt][nt] = __builtin_amdgcn_mfma_f32_16x16x32_f16(
                    af[mt], bf[nt], acc[mt][nt], 0, 0, 0);
    }

#pragma unroll
    for (int nt = 0; nt < 4; nt++) {
        const int n = n0 + wn + nt * 16 + lc;          // h*64 + d
        const float bv_ = bias[n];
        const int h = n >> 6, d = n & 63;
#pragma unroll
        for (int mt = 0; mt < 4; mt++) {
#pragma unroll
            for (int r = 0; r < 4; r++) {
                const int m = m0 + wm + mt * 16 + quad * 4 + r;   // b*S + s
                const int b = m >> 11, s = m & (S_LEN - 1);
                const int bh = b * NHEAD + h;
                float y = acc[mt][nt][r] + bv_;
                if (z == 0) y *= LOG2E;                 // exp2-fold for attn
                _Float16 val = (_Float16)y;
                if (z == 2)
                    Y[((size_t)bh * HD + d) * S_LEN + s] = val;          // V^T
                else
                    Y[((size_t)bh * S_LEN + s) * HD + d] = val;          // Q,K
            }
        }
    }
}

// ---------------------------------------------------------------------------
// Flash attention v4.  R2 post-mortem: LDS XOR-swizzle removed counted-but-
// free b128 serialization while ADDING real per-access address VALU (+12us).
// This round: R0's padded [64][72] layout (one LDS base VGPR + immediate
// offsets, zero per-access addressing) + strict instruction deletions:
//   * mask bias folded into MFMA C-init (kills 32 v_add/wave-tile)
//   * __builtin_amdgcn_exp2f (single v_exp_f32; Q pre-scaled by log2e)
//   * v_max3 tree for row max (15 -> 8 ops), pairwise sum tree
//   * cvt_pkrtz packed P, defer-max (T13), XCD-aware block swizzle kept.
// Orientation: S^T = K.Q^T, O^T = V^T.P^T (transposed MFMA), 128-row tiles,
// 4 waves, 2 q-groups/wave (each K/V LDS read feeds 2 MFMAs).
// ---------------------------------------------------------------------------
__global__ __launch_bounds__(256) void flash_attn_mfma(
    const _Float16* __restrict__ Qb, const _Float16* __restrict__ Kb,
    const _Float16* __restrict__ Vtb, const int* __restrict__ mask,
    float* __restrict__ out)
{
    // XCD swizzle: each XCD gets 64 consecutive logical blocks = 4 bh groups
    // x 16 q-tiles -> its L2 holds K/V for 4 heads (2MB, resident).
    const int bid = blockIdx.x;                  // 0..511
    const int swz = (bid & 7) * 64 + (bid >> 3);
    const int qt = swz & 15;                     // 16 q-tiles of 128 rows
    const int bh = swz >> 4;                     // 0..31
    const int b  = bh >> 4;
    const int h  = bh & (NHEAD - 1);

    __shared__ __align__(16) _Float16 Ks [64][72];      // [key][d]
    __shared__ __align__(16) _Float16 Vts[64][72];      // [d][key]
    __shared__ __align__(16) _Float16 Ps [4][32][72];   // per-wave P, [q][key]
    __shared__ float biasS[64];                         // mask bias per key

    const int t    = threadIdx.x;
    const int w    = t >> 6;
    const int lane = t & 63;
    const int quad = lane >> 4;
    const int lc   = lane & 15;

    const _Float16* Kbase = Kb  + (size_t)bh * S_LEN * HD;
    const _Float16* Vbase = Vtb + (size_t)bh * HD * S_LEN;
    const int* mbase = mask + b * S_LEN;

    // Q B-frags: qg in {0,1}, q-row = qt*128 + w*32 + qg*16 + lc
    half8 qf[2][2];
#pragma unroll
    for (int qg = 0; qg < 2; qg++) {
        const int qrow = qt * 128 + w * 32 + qg * 16 + lc;
#pragma unroll
        for (int s = 0; s < 2; s++)
            qf[qg][s] = *(const half8*)(Qb + ((size_t)bh * S_LEN + qrow) * HD
                                        + s * 32 + quad * 8);
    }

    f32x4 o[2][4];                      // O^T per qg: d = nt*16+quad*4+r, q = lc
    const f32x4 fzero = {0.f, 0.f, 0.f, 0.f};
#pragma unroll
    for (int qg = 0; qg < 2; qg++)
#pragma unroll
        for (int nt = 0; nt < 4; nt++) o[qg][nt] = fzero;
    float mrun[2] = {-3.0e38f, -3.0e38f};
    float lrun[2] = {0.f, 0.f};

    // staging geometry: chunk c = t + 256*i -> row c>>3, col (c&7)*8
    const int rr0 = t >> 3,          cc0 = (t & 7) * 8;
    const int rr1 = (t + 256) >> 3;                       // rows 32..63

    half8 kpre[2], vpre[2];
    int   mpre;
#define ATTN_ISSUE(KT)                                                        \
    {                                                                         \
        kpre[0] = *(const half8*)(Kbase + (size_t)((KT) + rr0) * HD + cc0);   \
        kpre[1] = *(const half8*)(Kbase + (size_t)((KT) + rr1) * HD + cc0);   \
        vpre[0] = *(const half8*)(Vbase + (size_t)rr0 * S_LEN + (KT) + cc0);  \
        vpre[1] = *(const half8*)(Vbase + (size_t)rr1 * S_LEN + (KT) + cc0);  \
        mpre    = mbase[(KT) + (t & 63)];                                     \
    }

    ATTN_ISSUE(0)

    for (int kt = 0; kt < S_LEN; kt += 64) {
        if (kt) __syncthreads();        // prev iter done reading LDS
        *(half8*)&Ks [rr0][cc0] = kpre[0];
        *(half8*)&Ks [rr1][cc0] = kpre[1];
        *(half8*)&Vts[rr0][cc0] = vpre[0];
        *(half8*)&Vts[rr1][cc0] = vpre[1];
        if (t < 64) biasS[t] = mpre ? 0.f : NEGBIAS;
        __syncthreads();

        if (kt + 64 < S_LEN) ATTN_ISSUE(kt + 64)   // overlap with compute

        // S^T = K.Q^T, mask bias pre-loaded into the MFMA C operand.
        // scf[qg][tt][r] is key tt*16+quad*4+r, q = lc  (bias = f(key) only).
        f32x4 scf[2][4];
#pragma unroll
        for (int tt = 0; tt < 4; tt++) {
            float4 b4 = *(const float4*)&biasS[tt * 16 + quad * 4];
            f32x4 cini = {b4.x, b4.y, b4.z, b4.w};
            scf[0][tt] = cini;
            scf[1][tt] = cini;
        }
#pragma unroll
        for (int s = 0; s < 2; s++) {
#pragma unroll
            for (int tt = 0; tt < 4; tt++) {
                half8 kf = *(const half8*)&Ks[tt * 16 + lc][s * 32 + quad * 8];
                scf[0][tt] = __builtin_amdgcn_mfma_f32_16x16x32_f16(kf, qf[0][s], scf[0][tt], 0, 0, 0);
                scf[1][tt] = __builtin_amdgcn_mfma_f32_16x16x32_f16(kf, qf[1][s], scf[1][tt], 0, 0, 0);
            }
        }

        // per-lane online softmax, one q-row per (qg, lc), log2 domain
#pragma unroll
        for (int qg = 0; qg < 2; qg++) {
            const f32x4 a0 = scf[qg][0], a1 = scf[qg][1],
                        a2 = scf[qg][2], a3 = scf[qg][3];
            float m0 = max3f(a0[0], a0[1], a0[2]);
            float m1 = max3f(a0[3], a1[0], a1[1]);
            float m2 = max3f(a1[2], a1[3], a2[0]);
            float m3 = max3f(a2[1], a2[2], a2[3]);
            float m4 = max3f(a3[0], a3[1], a3[2]);
            float mx = fmaxf(max3f(m0, m1, m2), max3f(m3, m4, a3[3]));
            mx = fmaxf(mx, __shfl_xor(mx, 16));
            mx = fmaxf(mx, __shfl_xor(mx, 32));

            // defer-max (T13): skip o-rescale unless max grew past threshold.
            // While deferred, P is bounded by 2^8 = 256 (fine in f16).
            if (!__all(mx <= mrun[qg] + 8.f)) {
                float mn = fmaxf(mrun[qg], mx);
                float al = __builtin_amdgcn_exp2f(mrun[qg] - mn);
                lrun[qg] *= al;
#pragma unroll
                for (int nt = 0; nt < 4; nt++) {
                    o[qg][nt][0] *= al; o[qg][nt][1] *= al;
                    o[qg][nt][2] *= al; o[qg][nt][3] *= al;
                }
                mrun[qg] = mn;
            }

            const float mr = mrun[qg];
            float ps[4][4];
#pragma unroll
            for (int tt = 0; tt < 4; tt++)
#pragma unroll
                for (int r = 0; r < 4; r++) {
                    float p = __builtin_amdgcn_exp2f(scf[qg][tt][r] - mr);
                    ps[tt][r] = p;
                }
            // pairwise sum tree
            float s0 = (ps[0][0] + ps[0][1]) + (ps[0][2] + ps[0][3]);
            float s1 = (ps[1][0] + ps[1][1]) + (ps[1][2] + ps[1][3]);
            float s2 = (ps[2][0] + ps[2][1]) + (ps[2][2] + ps[2][3]);
            float s3 = (ps[3][0] + ps[3][1]) + (ps[3][2] + ps[3][3]);
            float ls = (s0 + s1) + (s2 + s3);
            ls += __shfl_xor(ls, 16);
            ls += __shfl_xor(ls, 32);
            lrun[qg] += ls;

            // P rows (q-major): Ps[w][qg*16+lc][key], packed RTZ conversion
#pragma unroll
            for (int tt = 0; tt < 4; tt++) {
                fp16x2 p01 = __builtin_amdgcn_cvt_pkrtz(ps[tt][0], ps[tt][1]);
                fp16x2 p23 = __builtin_amdgcn_cvt_pkrtz(ps[tt][2], ps[tt][3]);
                fp16x4 pk4 = __builtin_shufflevector(p01, p23, 0, 1, 2, 3);
                *(half4*)&Ps[w][qg * 16 + lc][tt * 16 + quad * 4] =
                    __builtin_bit_cast(half4, pk4);
            }
        }

        // O^T += V^T.P^T : each vf read feeds both qg MFMAs
#pragma unroll
        for (int s = 0; s < 2; s++) {
            half8 pf0 = *(const half8*)&Ps[w][lc]     [s * 32 + quad * 8];
            half8 pf1 = *(const half8*)&Ps[w][16 + lc][s * 32 + quad * 8];
#pragma unroll
            for (int nt = 0; nt < 4; nt++) {
                half8 vf = *(const half8*)&Vts[nt * 16 + lc][s * 32 + quad * 8];
                o[0][nt] = __builtin_amdgcn_mfma_f32_16x16x32_f16(vf, pf0, o[0][nt], 0, 0, 0);
                o[1][nt] = __builtin_amdgcn_mfma_f32_16x16x32_f16(vf, pf1, o[1][nt], 0, 0, 0);
            }
        }
    }

    // epilogue: lane owns q-row per qg; contiguous float4 stores
#pragma unroll
    for (int qg = 0; qg < 2; qg++) {
        const int qrow = qt * 128 + w * 32 + qg * 16 + lc;
        const float inv = 1.f / lrun[qg];
        const size_t rowb = ((size_t)b * S_LEN + qrow) * HDIM + h * HD;
#pragma unroll
        for (int nt = 0; nt < 4; nt++) {
            float4 v;
            v.x = o[qg][nt][0] * inv; v.y = o[qg][nt][1] * inv;
            v.z = o[qg][nt][2] * inv; v.w = o[qg][nt][3] * inv;
            *(float4*)&out[rowb + nt * 16 + quad * 4] = v;
        }
    }
}

// ---------------------------------------------------------------------------
extern "C" void kernel_launch(void* const* d_in, const int* in_sizes, int n_in,
                              void* d_out, int out_size, void* d_ws, size_t ws_size,
                              hipStream_t stream) {
    const float* query = (const float*)d_in[0];
    const float* key   = (const float*)d_in[1];
    const float* value = (const float*)d_in[2];
    const int*   mask  = (const int*)  d_in[3];
    const float* Wq    = (const float*)d_in[4];
    const float* bq    = (const float*)d_in[5];
    const float* Wk    = (const float*)d_in[6];
    const float* bk    = (const float*)d_in[7];
    const float* Wv    = (const float*)d_in[8];
    const float* bv    = (const float*)d_in[9];
    float* out = (float*)d_out;

    const size_t nElem = (size_t)BATCH * S_LEN * HDIM;          // 4M
    if (ws_size < 3 * nElem * sizeof(_Float16)) return;         // 24 MB
    _Float16* Qb  = (_Float16*)d_ws;
    _Float16* Kb  = Qb + nElem;
    _Float16* Vtb = Kb + nElem;

    dim3 gproj(HDIM / 128, (BATCH * S_LEN) / 128, 3);           // (8, 32, 3)
    proj_gemm_f16<<<gproj, 256, 0, stream>>>(query, Wq, bq, key, Wk, bk,
                                             value, Wv, bv, Qb, Kb, Vtb);

    flash_attn_mfma<<<BATCH * NHEAD * (S_LEN / 128), 256, 0, stream>>>(
        Qb, Kb, Vtb, mask, out);
}